// Round 1
// baseline (137.198 us; speedup 1.0000x reference)
//
#include <hip/hip_runtime.h>
#include <hip/hip_bf16.h>

#define MDIM 8192
#define KDIM 256
#define INV_TEMP 10.0f

typedef __attribute__((ext_vector_type(8))) short short8;
typedef __attribute__((ext_vector_type(4))) float f32x4;

// Kernel 1: row-normalize (fp32 in, bf16 out). One block per row, 256 threads.
__global__ __launch_bounds__(256) void knorm(const float* __restrict__ x,
                                             __hip_bfloat16* __restrict__ xn) {
    const int row = blockIdx.x;
    const int t = threadIdx.x;
    const float v = x[(size_t)row * KDIM + t];
    float ss = v * v;
#pragma unroll
    for (int m = 1; m < 64; m <<= 1) ss += __shfl_xor(ss, m, 64);
    __shared__ float wsum[4];
    if ((t & 63) == 0) wsum[t >> 6] = ss;
    __syncthreads();
    const float tot = wsum[0] + wsum[1] + wsum[2] + wsum[3];
    const float inv = 1.0f / fmaxf(sqrtf(tot), 1e-8f);
    xn[(size_t)row * KDIM + t] = __float2bfloat16(v * inv);
}

// Kernel 2: fused sim = (Xn Xn^T)/TEMP with epilogue:
//   row_sum[i] += sum_{j != i, j in col-block} exp(sim_ij)   (atomicAdd per row per block)
//   pos[i] = sim[i, i^4096]                                   (unique writer)
// 128x128 tile, 4 waves (2x2), each wave 64x64 via 4x4 frags of 16x16x32 bf16 MFMA.
__global__ __launch_bounds__(256) void ksim(const ushort* __restrict__ xn,
                                            float* __restrict__ row_sum,
                                            float* __restrict__ pos) {
    __shared__ ushort As[128][72];  // +8 bf16 pad: rows 16B-aligned, banks spread
    __shared__ ushort Bs[128][72];

    const int bi = blockIdx.y, bj = blockIdx.x;
    const int rowBase = bi * 128, colBase = bj * 128;
    const int t = threadIdx.x;
    const int wave = t >> 6, lane = t & 63;
    const int l16 = lane & 15, lhi = lane >> 4;
    const int wRow = (wave >> 1) * 64, wCol = (wave & 1) * 64;

    f32x4 acc[4][4];
#pragma unroll
    for (int a = 0; a < 4; ++a)
#pragma unroll
        for (int b = 0; b < 4; ++b) acc[a][b] = (f32x4){0.f, 0.f, 0.f, 0.f};

    for (int ks = 0; ks < 4; ++ks) {
        const int kk = ks * 64;
        // stage A and B tiles: 128 rows x 64 bf16 each; 256 threads x 8 bf16 x 4 iters
#pragma unroll
        for (int it = 0; it < 4; ++it) {
            const int idx = (it * 256 + t) * 8;
            const int r = idx >> 6, c = idx & 63;
            const uint4 va = *reinterpret_cast<const uint4*>(
                xn + (size_t)(rowBase + r) * KDIM + kk + c);
            *reinterpret_cast<uint4*>(&As[r][c]) = va;
            const uint4 vb = *reinterpret_cast<const uint4*>(
                xn + (size_t)(colBase + r) * KDIM + kk + c);
            *reinterpret_cast<uint4*>(&Bs[r][c]) = vb;
        }
        __syncthreads();
#pragma unroll
        for (int k2 = 0; k2 < 2; ++k2) {
            const int ko = k2 * 32 + lhi * 8;
            short8 a[4], b[4];
#pragma unroll
            for (int f = 0; f < 4; ++f)
                a[f] = *reinterpret_cast<const short8*>(&As[wRow + f * 16 + l16][ko]);
#pragma unroll
            for (int f = 0; f < 4; ++f)
                b[f] = *reinterpret_cast<const short8*>(&Bs[wCol + f * 16 + l16][ko]);
#pragma unroll
            for (int fr = 0; fr < 4; ++fr)
#pragma unroll
                for (int fc = 0; fc < 4; ++fc)
                    acc[fr][fc] = __builtin_amdgcn_mfma_f32_16x16x32_bf16(
                        a[fr], b[fc], acc[fr][fc], 0, 0, 0);
        }
        __syncthreads();
    }

    // Epilogue. C/D layout (m89-verified): col = lane&15, row = (lane>>4)*4 + reg.
#pragma unroll
    for (int fr = 0; fr < 4; ++fr) {
        float psum[4] = {0.f, 0.f, 0.f, 0.f};
#pragma unroll
        for (int fc = 0; fc < 4; ++fc) {
            const int gj = colBase + wCol + fc * 16 + l16;
#pragma unroll
            for (int j = 0; j < 4; ++j) {
                const int gi = rowBase + wRow + fr * 16 + lhi * 4 + j;
                const float v = acc[fr][fc][j] * INV_TEMP;
                if (gj == (gi ^ 4096)) pos[gi] = v;
                psum[j] += (gi == gj) ? 0.0f : __expf(v);
            }
        }
#pragma unroll
        for (int j = 0; j < 4; ++j) {
            float s = psum[j];
            s += __shfl_xor(s, 1, 16);
            s += __shfl_xor(s, 2, 16);
            s += __shfl_xor(s, 4, 16);
            s += __shfl_xor(s, 8, 16);
            if (l16 == 0) {
                const int gi = rowBase + wRow + fr * 16 + lhi * 4 + j;
                atomicAdd(&row_sum[gi], s);
            }
        }
    }
}

// Kernel 3: loss = mean_i( log(row_sum[i]) - pos[i] )
__global__ __launch_bounds__(256) void kfinal(const float* __restrict__ row_sum,
                                              const float* __restrict__ pos,
                                              float* __restrict__ out) {
    float acc = 0.f;
    for (int i = threadIdx.x; i < MDIM; i += 256)
        acc += logf(row_sum[i]) - pos[i];
#pragma unroll
    for (int m = 1; m < 64; m <<= 1) acc += __shfl_xor(acc, m, 64);
    __shared__ float w[4];
    if ((threadIdx.x & 63) == 0) w[threadIdx.x >> 6] = acc;
    __syncthreads();
    if (threadIdx.x == 0) out[0] = (w[0] + w[1] + w[2] + w[3]) / (float)MDIM;
}

extern "C" void kernel_launch(void* const* d_in, const int* in_sizes, int n_in,
                              void* d_out, int out_size, void* d_ws, size_t ws_size,
                              hipStream_t stream) {
    const float* x = (const float*)d_in[0];
    float* out = (float*)d_out;

    char* ws = (char*)d_ws;
    __hip_bfloat16* xn = (__hip_bfloat16*)ws;                       // 8192*256*2 = 4 MB
    float* row_sum = (float*)(ws + (size_t)MDIM * KDIM * 2);        // 32 KB
    float* pos = row_sum + MDIM;                                    // 32 KB

    hipMemsetAsync(row_sum, 0, MDIM * sizeof(float), stream);

    knorm<<<MDIM, 256, 0, stream>>>(x, xn);

    dim3 grid(MDIM / 128, MDIM / 128);
    ksim<<<grid, 256, 0, stream>>>((const ushort*)xn, row_sum, pos);

    kfinal<<<1, 256, 0, stream>>>(row_sum, pos, out);
}

// Round 2
// 80.879 us; speedup vs baseline: 1.6963x; 1.6963x over previous
//
#include <hip/hip_runtime.h>
#include <hip/hip_bf16.h>

#define MDIM 8192
#define KDIM 256
#define INV_TEMP 10.0f
#define NB 64  // 8192 / 128 block-tiles per dim

typedef __attribute__((ext_vector_type(8))) short short8;
typedef __attribute__((ext_vector_type(4))) float f32x4;

__device__ __forceinline__ ushort bf16u(float f) {
    __hip_bfloat16 h = __float2bfloat16(f);
    return *reinterpret_cast<ushort*>(&h);
}

// Kernel 1: row-normalize (fp32 in, bf16 out). 1 wave per row, 4 rows/block.
__global__ __launch_bounds__(256) void knorm(const float* __restrict__ x,
                                             ushort* __restrict__ xn) {
    const int wave = threadIdx.x >> 6, lane = threadIdx.x & 63;
    const int row = blockIdx.x * 4 + wave;
    const float4 v = *reinterpret_cast<const float4*>(x + (size_t)row * KDIM + lane * 4);
    float ss = v.x * v.x + v.y * v.y + v.z * v.z + v.w * v.w;
#pragma unroll
    for (int m = 1; m < 64; m <<= 1) ss += __shfl_xor(ss, m, 64);
    const float inv = 1.0f / fmaxf(sqrtf(ss), 1e-8f);
    ushort4 o;
    o.x = bf16u(v.x * inv);
    o.y = bf16u(v.y * inv);
    o.z = bf16u(v.z * inv);
    o.w = bf16u(v.w * inv);
    *reinterpret_cast<ushort4*>(xn + (size_t)row * KDIM + lane * 4) = o;
}

// Kernel 2: upper-triangle block tiles of sim = (Xn Xn^T)/TEMP.
// Off-diagonal block (bi<bj): every exp(v_ij) is added to row_sum[i] AND row_sum[j]
// (symmetry). Diagonal block: row sums only, diagonal element excluded, B tile = A tile.
// LDS: linear [128][64] ushort with XOR swizzle (idx = r*64 + (c ^ ((r&7)<<3))),
// conflict-free for both the 16B staging writes and the ds_read_b128 fragment reads.
__global__ __launch_bounds__(256) void ksim(const ushort* __restrict__ xn,
                                            float* __restrict__ row_sum,
                                            float* __restrict__ pos) {
    __shared__ ushort As[128 * 64];
    __shared__ ushort Bs[128 * 64];

    // map linear block id -> (bi, bj), bj >= bi (row-major upper triangle)
    const int tb = blockIdx.x;
    int bi = (int)((129.0f - sqrtf(16641.0f - 8.0f * (float)tb)) * 0.5f);
    while (NB * bi - bi * (bi - 1) / 2 > tb) --bi;
    while (NB * (bi + 1) - (bi + 1) * bi / 2 <= tb) ++bi;
    const int bj = bi + (tb - (NB * bi - bi * (bi - 1) / 2));
    const bool diag = (bi == bj);
    const bool pblk = (bj == bi + 32);  // blocks containing (i, i^4096) pairs

    const int rowBase = bi * 128, colBase = bj * 128;
    const int t = threadIdx.x;
    const int wave = t >> 6, lane = t & 63;
    const int l16 = lane & 15, lhi = lane >> 4;
    const int wRow = (wave >> 1) * 64, wCol = (wave & 1) * 64;

    f32x4 acc[4][4];
#pragma unroll
    for (int a = 0; a < 4; ++a)
#pragma unroll
        for (int b = 0; b < 4; ++b) acc[a][b] = (f32x4){0.f, 0.f, 0.f, 0.f};

    const ushort* Bsel = diag ? As : Bs;
    const int sw = (l16 & 7) << 3;  // fragment-read swizzle (row%8 == l16%8)

    for (int ks = 0; ks < 4; ++ks) {
        const int kk = ks * 64;
#pragma unroll
        for (int it = 0; it < 4; ++it) {
            const int idx = (it * 256 + t) * 8;
            const int r = idx >> 6, c = idx & 63;
            const int sidx = r * 64 + (c ^ ((r & 7) << 3));
            *reinterpret_cast<uint4*>(&As[sidx]) = *reinterpret_cast<const uint4*>(
                xn + (size_t)(rowBase + r) * KDIM + kk + c);
            if (!diag)
                *reinterpret_cast<uint4*>(&Bs[sidx]) = *reinterpret_cast<const uint4*>(
                    xn + (size_t)(colBase + r) * KDIM + kk + c);
        }
        __syncthreads();
#pragma unroll
        for (int k2 = 0; k2 < 2; ++k2) {
            const int ko = k2 * 32 + lhi * 8;
            short8 a[4], b[4];
#pragma unroll
            for (int f = 0; f < 4; ++f)
                a[f] = *reinterpret_cast<const short8*>(
                    &As[(wRow + f * 16 + l16) * 64 + (ko ^ sw)]);
#pragma unroll
            for (int f = 0; f < 4; ++f)
                b[f] = *reinterpret_cast<const short8*>(
                    &Bsel[(wCol + f * 16 + l16) * 64 + (ko ^ sw)]);
#pragma unroll
            for (int fr = 0; fr < 4; ++fr)
#pragma unroll
                for (int fc = 0; fc < 4; ++fc)
                    acc[fr][fc] = __builtin_amdgcn_mfma_f32_16x16x32_bf16(
                        a[fr], b[fc], acc[fr][fc], 0, 0, 0);
        }
        __syncthreads();
    }

    // Epilogue. C/D layout (m89-verified): col = lane&15, row = (lane>>4)*4 + reg.
    if (diag) {
#pragma unroll
        for (int fr = 0; fr < 4; ++fr) {
            float psum[4] = {0.f, 0.f, 0.f, 0.f};
#pragma unroll
            for (int fc = 0; fc < 4; ++fc) {
                const int gj = colBase + wCol + fc * 16 + l16;
#pragma unroll
                for (int j = 0; j < 4; ++j) {
                    const int gi = rowBase + wRow + fr * 16 + lhi * 4 + j;
                    const float v = acc[fr][fc][j] * INV_TEMP;
                    psum[j] += (gi == gj) ? 0.0f : __expf(v);
                }
            }
#pragma unroll
            for (int j = 0; j < 4; ++j) {
                float s = psum[j];
                s += __shfl_xor(s, 1, 16);
                s += __shfl_xor(s, 2, 16);
                s += __shfl_xor(s, 4, 16);
                s += __shfl_xor(s, 8, 16);
                if (l16 == 0)
                    atomicAdd(&row_sum[rowBase + wRow + fr * 16 + lhi * 4 + j], s);
            }
        }
    } else {
        float csum[4] = {0.f, 0.f, 0.f, 0.f};
#pragma unroll
        for (int fr = 0; fr < 4; ++fr) {
            float psum[4] = {0.f, 0.f, 0.f, 0.f};
#pragma unroll
            for (int fc = 0; fc < 4; ++fc) {
#pragma unroll
                for (int j = 0; j < 4; ++j) {
                    const float v = acc[fr][fc][j] * INV_TEMP;
                    const float e = __expf(v);
                    psum[j] += e;
                    csum[fc] += e;
                    if (pblk) {
                        const int gi = rowBase + wRow + fr * 16 + lhi * 4 + j;
                        const int gj = colBase + wCol + fc * 16 + l16;
                        if (gj == (gi ^ 4096)) {
                            pos[gi] = v;
                            pos[gj] = v;
                        }
                    }
                }
            }
#pragma unroll
            for (int j = 0; j < 4; ++j) {
                float s = psum[j];
                s += __shfl_xor(s, 1, 16);
                s += __shfl_xor(s, 2, 16);
                s += __shfl_xor(s, 4, 16);
                s += __shfl_xor(s, 8, 16);
                if (l16 == 0)
                    atomicAdd(&row_sum[rowBase + wRow + fr * 16 + lhi * 4 + j], s);
            }
        }
#pragma unroll
        for (int fc = 0; fc < 4; ++fc) {
            float s = csum[fc];
            s += __shfl_xor(s, 16, 64);
            s += __shfl_xor(s, 32, 64);
            if (lhi == 0)
                atomicAdd(&row_sum[colBase + wCol + fc * 16 + l16], s);
        }
    }
}

// Kernel 3: loss = mean_i( log(row_sum[i]) - pos[i] )
__global__ __launch_bounds__(1024) void kfinal(const float* __restrict__ row_sum,
                                               const float* __restrict__ pos,
                                               float* __restrict__ out) {
    float acc = 0.f;
    for (int i = threadIdx.x; i < MDIM; i += 1024)
        acc += logf(row_sum[i]) - pos[i];
#pragma unroll
    for (int m = 1; m < 64; m <<= 1) acc += __shfl_xor(acc, m, 64);
    __shared__ float w[16];
    if ((threadIdx.x & 63) == 0) w[threadIdx.x >> 6] = acc;
    __syncthreads();
    if (threadIdx.x == 0) {
        float s = 0.f;
#pragma unroll
        for (int i = 0; i < 16; ++i) s += w[i];
        out[0] = s / (float)MDIM;
    }
}

extern "C" void kernel_launch(void* const* d_in, const int* in_sizes, int n_in,
                              void* d_out, int out_size, void* d_ws, size_t ws_size,
                              hipStream_t stream) {
    const float* x = (const float*)d_in[0];
    float* out = (float*)d_out;

    char* ws = (char*)d_ws;
    ushort* xn = (ushort*)ws;                                  // 8192*256*2 = 4 MB
    float* row_sum = (float*)(ws + (size_t)MDIM * KDIM * 2);   // 32 KB
    float* pos = row_sum + MDIM;                               // 32 KB

    hipMemsetAsync(row_sum, 0, MDIM * sizeof(float), stream);

    knorm<<<MDIM / 4, 256, 0, stream>>>(x, xn);

    const int nblocks = NB * (NB + 1) / 2;  // 2080 upper-triangle tiles
    ksim<<<nblocks, 256, 0, stream>>>(xn, row_sum, pos);

    kfinal<<<1, 1024, 0, stream>>>(row_sum, pos, out);
}

// Round 3
// 68.352 us; speedup vs baseline: 2.0072x; 1.1833x over previous
//
#include <hip/hip_runtime.h>
#include <hip/hip_bf16.h>

#define MDIM 8192
#define KDIM 256
#define INV_TEMP 10.0f
#define NB 64  // 8192 / 128 block-tiles per dim

typedef __attribute__((ext_vector_type(8))) short short8;
typedef __attribute__((ext_vector_type(4))) float f32x4;

__device__ __forceinline__ ushort bf16u(float f) {
    __hip_bfloat16 h = __float2bfloat16(f);
    return *reinterpret_cast<ushort*>(&h);
}

// async global->LDS, 16B per lane. LDS dest is wave-uniform base + lane*16.
__device__ __forceinline__ void async16(ushort* lds, const ushort* g) {
    __builtin_amdgcn_global_load_lds(
        (const __attribute__((address_space(1))) void*)g,
        (__attribute__((address_space(3))) void*)lds, 16, 0, 0);
}

// Kernel 1: row-normalize (fp32 in, bf16 out) + zero row_sum. 4 rows/block.
__global__ __launch_bounds__(256) void knorm(const float* __restrict__ x,
                                             ushort* __restrict__ xn,
                                             float* __restrict__ row_sum) {
    const int wave = threadIdx.x >> 6, lane = threadIdx.x & 63;
    const int row = blockIdx.x * 4 + wave;
    if (threadIdx.x < 4) row_sum[blockIdx.x * 4 + threadIdx.x] = 0.0f;
    const float4 v = *reinterpret_cast<const float4*>(x + (size_t)row * KDIM + lane * 4);
    float ss = v.x * v.x + v.y * v.y + v.z * v.z + v.w * v.w;
#pragma unroll
    for (int m = 1; m < 64; m <<= 1) ss += __shfl_xor(ss, m, 64);
    const float inv = 1.0f / fmaxf(sqrtf(ss), 1e-8f);
    ushort4 o;
    o.x = bf16u(v.x * inv);
    o.y = bf16u(v.y * inv);
    o.z = bf16u(v.z * inv);
    o.w = bf16u(v.w * inv);
    *reinterpret_cast<ushort4*>(xn + (size_t)row * KDIM + lane * 4) = o;
}

// Kernel 2: upper-triangle block tiles of sim = (Xn Xn^T)/TEMP, symmetry-folded
// row/col exp-sums, pos capture. Staging: global_load_lds dwordx4 into linear LDS
// with the XOR swizzle pre-applied to the GLOBAL source column (rule 21); reads use
// the matching swizzled ds_read_b128 (conflict-free, 0 SQ_LDS_BANK_CONFLICT in R2).
// Pipeline: 4 K-chunks of 64, double-buffered, counted vmcnt(8) + raw s_barrier.
__global__ __launch_bounds__(256) void ksim(const ushort* __restrict__ xn,
                                            float* __restrict__ row_sum,
                                            float* __restrict__ pos) {
    __shared__ ushort As[2][128 * 64];
    __shared__ ushort Bs[2][128 * 64];

    // map linear block id -> (bi, bj), bj >= bi (row-major upper triangle)
    const int tb = blockIdx.x;
    int bi = (int)((129.0f - sqrtf(16641.0f - 8.0f * (float)tb)) * 0.5f);
    while (NB * bi - bi * (bi - 1) / 2 > tb) --bi;
    while (NB * (bi + 1) - (bi + 1) * bi / 2 <= tb) ++bi;
    const int bj = bi + (tb - (NB * bi - bi * (bi - 1) / 2));
    const bool diag = (bi == bj);
    const bool pblk = (bj == bi + 32);  // blocks containing (i, i^4096) pairs

    const int rowBase = bi * 128, colBase = bj * 128;
    const int t = threadIdx.x;
    const int wave = t >> 6, lane = t & 63;
    const int l16 = lane & 15, lhi = lane >> 4;
    const int wRow = (wave >> 1) * 64, wCol = (wave & 1) * 64;

    // staging geometry: wave w, round q covers LDS ushort idx (w*4+q)*512 + lane*8
    // => row = (w*4+q)*8 + (lane>>3), col = (lane&7)*8. Source col gets the
    // involution: 8*((lane&7) ^ (lane>>3))  (row&7 == lane>>3).
    const int srcc = 8 * ((lane & 7) ^ (lane >> 3));
    const int subrow = lane >> 3;

    auto stage = [&](int c, int b) {
        const int kk = c * 64;
#pragma unroll
        for (int q = 0; q < 4; ++q) {
            const int rr = (wave * 4 + q) * 8 + subrow;
            async16(&As[b][(wave * 4 + q) * 512],
                    xn + (size_t)(rowBase + rr) * KDIM + kk + srcc);
        }
#pragma unroll
        for (int q = 0; q < 4; ++q) {
            const int rr = (wave * 4 + q) * 8 + subrow;
            async16(&Bs[b][(wave * 4 + q) * 512],
                    xn + (size_t)(colBase + rr) * KDIM + kk + srcc);
        }
    };

    f32x4 acc[4][4];
#pragma unroll
    for (int a = 0; a < 4; ++a)
#pragma unroll
        for (int b = 0; b < 4; ++b) acc[a][b] = (f32x4){0.f, 0.f, 0.f, 0.f};

    const int sw = (l16 & 7) << 3;  // fragment-read swizzle (row%8 == l16%8)

    auto compute = [&](int b) {
#pragma unroll
        for (int k2 = 0; k2 < 2; ++k2) {
            const int ko = k2 * 32 + lhi * 8;
            short8 a[4], bb[4];
#pragma unroll
            for (int f = 0; f < 4; ++f)
                a[f] = *reinterpret_cast<const short8*>(
                    &As[b][(wRow + f * 16 + l16) * 64 + (ko ^ sw)]);
#pragma unroll
            for (int f = 0; f < 4; ++f)
                bb[f] = *reinterpret_cast<const short8*>(
                    &Bs[b][(wCol + f * 16 + l16) * 64 + (ko ^ sw)]);
#pragma unroll
            for (int fr = 0; fr < 4; ++fr)
#pragma unroll
                for (int fc = 0; fc < 4; ++fc)
                    acc[fr][fc] = __builtin_amdgcn_mfma_f32_16x16x32_bf16(
                        a[fr], bb[fc], acc[fr][fc], 0, 0, 0);
        }
    };

    // Pipeline: issue c0,c1 (16 outstanding/wave, 8 per chunk); counted vmcnt
    // keeps later chunks in flight across barriers (never drain to 0 mid-loop).
    stage(0, 0);
    stage(1, 1);
    asm volatile("s_waitcnt vmcnt(8)\n\ts_barrier" ::: "memory");  // c0 landed (all waves)
    compute(0);
    asm volatile("s_barrier" ::: "memory");                        // buf0 free
    stage(2, 0);
    asm volatile("s_waitcnt vmcnt(8)\n\ts_barrier" ::: "memory");  // c1 landed
    compute(1);
    asm volatile("s_barrier" ::: "memory");                        // buf1 free
    stage(3, 1);
    asm volatile("s_waitcnt vmcnt(8)\n\ts_barrier" ::: "memory");  // c2 landed
    compute(0);
    asm volatile("s_waitcnt vmcnt(0)\n\ts_barrier" ::: "memory");  // c3 landed
    compute(1);

    // Epilogue. C/D layout (m89-verified): col = lane&15, row = (lane>>4)*4 + reg.
    if (diag) {
#pragma unroll
        for (int fr = 0; fr < 4; ++fr) {
            float psum[4] = {0.f, 0.f, 0.f, 0.f};
#pragma unroll
            for (int fc = 0; fc < 4; ++fc) {
                const int gj = colBase + wCol + fc * 16 + l16;
#pragma unroll
                for (int j = 0; j < 4; ++j) {
                    const int gi = rowBase + wRow + fr * 16 + lhi * 4 + j;
                    const float v = acc[fr][fc][j] * INV_TEMP;
                    psum[j] += (gi == gj) ? 0.0f : __expf(v);
                }
            }
#pragma unroll
            for (int j = 0; j < 4; ++j) {
                float s = psum[j];
                s += __shfl_xor(s, 1, 16);
                s += __shfl_xor(s, 2, 16);
                s += __shfl_xor(s, 4, 16);
                s += __shfl_xor(s, 8, 16);
                if (l16 == 0)
                    atomicAdd(&row_sum[rowBase + wRow + fr * 16 + lhi * 4 + j], s);
            }
        }
    } else {
        float csum[4] = {0.f, 0.f, 0.f, 0.f};
#pragma unroll
        for (int fr = 0; fr < 4; ++fr) {
            float psum[4] = {0.f, 0.f, 0.f, 0.f};
#pragma unroll
            for (int fc = 0; fc < 4; ++fc) {
#pragma unroll
                for (int j = 0; j < 4; ++j) {
                    const float v = acc[fr][fc][j] * INV_TEMP;
                    const float e = __expf(v);
                    psum[j] += e;
                    csum[fc] += e;
                    if (pblk) {
                        const int gi = rowBase + wRow + fr * 16 + lhi * 4 + j;
                        const int gj = colBase + wCol + fc * 16 + l16;
                        if (gj == (gi ^ 4096)) {
                            pos[gi] = v;
                            pos[gj] = v;
                        }
                    }
                }
            }
#pragma unroll
            for (int j = 0; j < 4; ++j) {
                float s = psum[j];
                s += __shfl_xor(s, 1, 16);
                s += __shfl_xor(s, 2, 16);
                s += __shfl_xor(s, 4, 16);
                s += __shfl_xor(s, 8, 16);
                if (l16 == 0)
                    atomicAdd(&row_sum[rowBase + wRow + fr * 16 + lhi * 4 + j], s);
            }
        }
#pragma unroll
        for (int fc = 0; fc < 4; ++fc) {
            float s = csum[fc];
            s += __shfl_xor(s, 16, 64);
            s += __shfl_xor(s, 32, 64);
            if (lhi == 0)
                atomicAdd(&row_sum[colBase + wCol + fc * 16 + l16], s);
        }
    }
}

// Kernel 3: loss = mean_i( log(row_sum[i]) - pos[i] )
__global__ __launch_bounds__(1024) void kfinal(const float* __restrict__ row_sum,
                                               const float* __restrict__ pos,
                                               float* __restrict__ out) {
    float acc = 0.f;
    for (int i = threadIdx.x; i < MDIM; i += 1024)
        acc += logf(row_sum[i]) - pos[i];
#pragma unroll
    for (int m = 1; m < 64; m <<= 1) acc += __shfl_xor(acc, m, 64);
    __shared__ float w[16];
    if ((threadIdx.x & 63) == 0) w[threadIdx.x >> 6] = acc;
    __syncthreads();
    if (threadIdx.x == 0) {
        float s = 0.f;
#pragma unroll
        for (int i = 0; i < 16; ++i) s += w[i];
        out[0] = s / (float)MDIM;
    }
}

extern "C" void kernel_launch(void* const* d_in, const int* in_sizes, int n_in,
                              void* d_out, int out_size, void* d_ws, size_t ws_size,
                              hipStream_t stream) {
    const float* x = (const float*)d_in[0];
    float* out = (float*)d_out;

    char* ws = (char*)d_ws;
    ushort* xn = (ushort*)ws;                                  // 8192*256*2 = 4 MB
    float* row_sum = (float*)(ws + (size_t)MDIM * KDIM * 2);   // 32 KB
    float* pos = row_sum + MDIM;                               // 32 KB

    knorm<<<MDIM / 4, 256, 0, stream>>>(x, xn, row_sum);

    const int nblocks = NB * (NB + 1) / 2;  // 2080 upper-triangle tiles
    ksim<<<nblocks, 256, 0, stream>>>(xn, row_sum, pos);

    kfinal<<<1, 1024, 0, stream>>>(row_sum, pos, out);
}

// Round 4
// 49.326 us; speedup vs baseline: 2.7814x; 1.3857x over previous
//
#include <hip/hip_runtime.h>
#include <hip/hip_bf16.h>

#define MDIM 8192
#define KDIM 256
#define NB 64        // 8192/128 tiles per dim
#define NTILES 2080  // NB*(NB+1)/2 upper-triangle tiles
#define NBLK 512     // persistent blocks, 2 per CU

typedef __attribute__((ext_vector_type(8))) short short8;
typedef __attribute__((ext_vector_type(4))) float f32x4;

__device__ __forceinline__ ushort bf16u(float f) {
    __hip_bfloat16 h = __float2bfloat16(f);
    return *reinterpret_cast<ushort*>(&h);
}

// async global->LDS, 16B per lane; LDS dest = wave-uniform base + lane*16.
__device__ __forceinline__ void async16(ushort* lds, const ushort* g) {
    __builtin_amdgcn_global_load_lds(
        (const __attribute__((address_space(1))) void*)g,
        (__attribute__((address_space(3))) void*)lds, 16, 0, 0);
}

// Kernel 1: each wave owns the row pair (i, i+4096): normalizes both rows to bf16,
// computes pos[i] = pos[i+4096] = 10*cos(x_i, x_p) in fp32, zeros row_sum.
__global__ __launch_bounds__(256) void knorm(const float* __restrict__ x,
                                             ushort* __restrict__ xn,
                                             float* __restrict__ row_sum,
                                             float* __restrict__ pos) {
    const int wave = threadIdx.x >> 6, lane = threadIdx.x & 63;
    const int i = blockIdx.x * 4 + wave;  // 0..4095
    const int p = i + 4096;
    const float4 a = *reinterpret_cast<const float4*>(x + (size_t)i * KDIM + lane * 4);
    const float4 b = *reinterpret_cast<const float4*>(x + (size_t)p * KDIM + lane * 4);
    float sa = a.x * a.x + a.y * a.y + a.z * a.z + a.w * a.w;
    float sb = b.x * b.x + b.y * b.y + b.z * b.z + b.w * b.w;
    float sab = a.x * b.x + a.y * b.y + a.z * b.z + a.w * b.w;
#pragma unroll
    for (int m = 1; m < 64; m <<= 1) {
        sa += __shfl_xor(sa, m, 64);
        sb += __shfl_xor(sb, m, 64);
        sab += __shfl_xor(sab, m, 64);
    }
    const float ia = 1.0f / fmaxf(sqrtf(sa), 1e-8f);
    const float ib = 1.0f / fmaxf(sqrtf(sb), 1e-8f);
    ushort4 oa, ob;
    oa.x = bf16u(a.x * ia); oa.y = bf16u(a.y * ia);
    oa.z = bf16u(a.z * ia); oa.w = bf16u(a.w * ia);
    ob.x = bf16u(b.x * ib); ob.y = bf16u(b.y * ib);
    ob.z = bf16u(b.z * ib); ob.w = bf16u(b.w * ib);
    *reinterpret_cast<ushort4*>(xn + (size_t)i * KDIM + lane * 4) = oa;
    *reinterpret_cast<ushort4*>(xn + (size_t)p * KDIM + lane * 4) = ob;
    if (lane == 0) {
        const float pv = 10.0f * sab * ia * ib;
        pos[i] = pv;
        pos[p] = pv;
    }
    if (threadIdx.x < 8) row_sum[blockIdx.x * 8 + threadIdx.x] = 0.0f;
}

// Kernel 2: persistent blocks; each owns 4-5 upper-triangle 128x128 tiles
// (row-major triangle order). Flat double-buffered global_load_lds pipeline
// across tile boundaries, counted vmcnt(8). Off-diag tiles fold symmetric
// col-sums; row-sums accumulate in registers (prsum) and flush per bi-segment.
__global__ __launch_bounds__(256) void ksim(const ushort* __restrict__ xn,
                                            float* __restrict__ row_sum) {
    __shared__ ushort As[2][8192];
    __shared__ ushort Bs[2][8192];

    const int blk = blockIdx.x;
    const int tb0 = (blk * NTILES) >> 9;
    const int tend = ((blk + 1) * NTILES) >> 9;
    const int S = 4 * (tend - tb0);  // flat chunk-steps for this block

    // decode tb0 -> (bi, bj) in row-major upper triangle
    int bi = (int)((129.0f - sqrtf(16641.0f - 8.0f * (float)tb0)) * 0.5f);
    while (NB * bi - bi * (bi - 1) / 2 > tb0) --bi;
    while (NB * (bi + 1) - (bi + 1) * bi / 2 <= tb0) ++bi;
    int bj = bi + (tb0 - (NB * bi - bi * (bi - 1) / 2));

    const int t = threadIdx.x;
    const int wave = t >> 6, lane = t & 63;
    const int l16 = lane & 15, lhi = lane >> 4;
    const int wRow = (wave >> 1) * 64, wCol = (wave & 1) * 64;
    const bool wdiag = (wRow == wCol);
    const int srcc = 8 * ((lane & 7) ^ (lane >> 3));  // XOR-swizzle on global src col
    const int subrow = lane >> 3;
    const int sw = (l16 & 7) << 3;  // matching swizzle on ds_read

    // staging cursor (runs ahead of compute cursor)
    int sbi = bi, sbj = bj, sc = 0, sstep = 0;
    auto stage1 = [&]() {
        const size_t rbase = (size_t)sbi * 128 * KDIM;
        const size_t cbase = (size_t)sbj * 128 * KDIM;
        const int kk = sc * 64 + srcc;
        const int buf = sstep & 1;
#pragma unroll
        for (int q = 0; q < 4; ++q) {
            const int rr = (wave * 4 + q) * 8 + subrow;
            async16(&As[buf][(wave * 4 + q) * 512], xn + rbase + (size_t)rr * KDIM + kk);
        }
#pragma unroll
        for (int q = 0; q < 4; ++q) {
            const int rr = (wave * 4 + q) * 8 + subrow;
            async16(&Bs[buf][(wave * 4 + q) * 512], xn + cbase + (size_t)rr * KDIM + kk);
        }
        ++sstep;
        if (++sc == 4) {
            sc = 0;
            if (++sbj == NB) { ++sbi; sbj = sbi; }
        }
    };

    f32x4 acc[4][4];
    float prsum[4][4];
#pragma unroll
    for (int a = 0; a < 4; ++a)
#pragma unroll
        for (int b = 0; b < 4; ++b) {
            acc[a][b] = (f32x4){0.f, 0.f, 0.f, 0.f};
            prsum[a][b] = 0.f;
        }

    auto compute = [&](int buf) {
        __builtin_amdgcn_s_setprio(1);
#pragma unroll
        for (int k2 = 0; k2 < 2; ++k2) {
            const int ko = k2 * 32 + lhi * 8;
            short8 a[4], bb[4];
#pragma unroll
            for (int f = 0; f < 4; ++f)
                a[f] = *reinterpret_cast<const short8*>(
                    &As[buf][(wRow + f * 16 + l16) * 64 + (ko ^ sw)]);
#pragma unroll
            for (int f = 0; f < 4; ++f)
                bb[f] = *reinterpret_cast<const short8*>(
                    &Bs[buf][(wCol + f * 16 + l16) * 64 + (ko ^ sw)]);
#pragma unroll
            for (int fr = 0; fr < 4; ++fr)
#pragma unroll
                for (int fc = 0; fc < 4; ++fc)
                    acc[fr][fc] = __builtin_amdgcn_mfma_f32_16x16x32_bf16(
                        a[fr], bb[fc], acc[fr][fc], 0, 0, 0);
        }
        __builtin_amdgcn_s_setprio(0);
    };

    stage1();  // step 0
    stage1();  // step 1
    int cstep = 0;

    for (int tt = tb0; tt < tend; ++tt) {
#pragma unroll
        for (int c = 0; c < 4; ++c, ++cstep) {
            if (cstep == S - 1)
                asm volatile("s_waitcnt vmcnt(0)\n\ts_barrier" ::: "memory");
            else
                asm volatile("s_waitcnt vmcnt(8)\n\ts_barrier" ::: "memory");
            compute(cstep & 1);
            asm volatile("s_barrier" ::: "memory");
            if (sstep < S) stage1();  // overwrites buf just freed by the barrier
        }

        // ---- tile epilogue (registers only; overlaps in-flight loads) ----
        const bool diag = (bi == bj);
        if (diag) {
#pragma unroll
            for (int fr = 0; fr < 4; ++fr)
#pragma unroll
                for (int fc = 0; fc < 4; ++fc)
#pragma unroll
                    for (int j = 0; j < 4; ++j) {
                        float e = __expf(acc[fr][fc][j] * 10.0f);
                        if (wdiag && fr == fc && l16 == lhi * 4 + j) e = 0.0f;
                        prsum[fr][j] += e;
                    }
        } else {
            float csum[4] = {0.f, 0.f, 0.f, 0.f};
#pragma unroll
            for (int fr = 0; fr < 4; ++fr)
#pragma unroll
                for (int fc = 0; fc < 4; ++fc)
#pragma unroll
                    for (int j = 0; j < 4; ++j) {
                        const float e = __expf(acc[fr][fc][j] * 10.0f);
                        prsum[fr][j] += e;
                        csum[fc] += e;
                    }
#pragma unroll
            for (int fc = 0; fc < 4; ++fc) {
                float s = csum[fc];
                s += __shfl_xor(s, 16, 64);
                s += __shfl_xor(s, 32, 64);
                if (lhi == 0)
                    atomicAdd(&row_sum[bj * 128 + wCol + fc * 16 + l16], s);
            }
        }
#pragma unroll
        for (int a = 0; a < 4; ++a)
#pragma unroll
            for (int b2 = 0; b2 < 4; ++b2) acc[a][b2] = (f32x4){0.f, 0.f, 0.f, 0.f};

        // advance tile cursor; flush row partials when leaving a bi row (or at end)
        int nbi = bi, nbj = bj + 1;
        if (nbj == NB) { nbi = bi + 1; nbj = nbi; }
        if (tt == tend - 1 || nbi != bi) {
#pragma unroll
            for (int fr = 0; fr < 4; ++fr)
#pragma unroll
                for (int j = 0; j < 4; ++j) {
                    float s = prsum[fr][j];
                    s += __shfl_xor(s, 1, 16);
                    s += __shfl_xor(s, 2, 16);
                    s += __shfl_xor(s, 4, 16);
                    s += __shfl_xor(s, 8, 16);
                    if (l16 == 0)
                        atomicAdd(&row_sum[bi * 128 + wRow + fr * 16 + lhi * 4 + j], s);
                    prsum[fr][j] = 0.f;
                }
        }
        bi = nbi;
        bj = nbj;
    }
}

// Kernel 3: loss = mean_i( log(row_sum[i]) - pos[i] )
__global__ __launch_bounds__(1024) void kfinal(const float* __restrict__ row_sum,
                                               const float* __restrict__ pos,
                                               float* __restrict__ out) {
    float acc = 0.f;
    for (int i = threadIdx.x; i < MDIM; i += 1024)
        acc += logf(row_sum[i]) - pos[i];
#pragma unroll
    for (int m = 1; m < 64; m <<= 1) acc += __shfl_xor(acc, m, 64);
    __shared__ float w[16];
    if ((threadIdx.x & 63) == 0) w[threadIdx.x >> 6] = acc;
    __syncthreads();
    if (threadIdx.x == 0) {
        float s = 0.f;
#pragma unroll
        for (int i = 0; i < 16; ++i) s += w[i];
        out[0] = s / (float)MDIM;
    }
}

extern "C" void kernel_launch(void* const* d_in, const int* in_sizes, int n_in,
                              void* d_out, int out_size, void* d_ws, size_t ws_size,
                              hipStream_t stream) {
    const float* x = (const float*)d_in[0];
    float* out = (float*)d_out;

    char* ws = (char*)d_ws;
    ushort* xn = (ushort*)ws;                                  // 8192*256*2 = 4 MB
    float* row_sum = (float*)(ws + (size_t)MDIM * KDIM * 2);   // 32 KB
    float* pos = row_sum + MDIM;                               // 32 KB

    knorm<<<MDIM / 8, 256, 0, stream>>>(x, xn, row_sum, pos);
    ksim<<<NBLK, 256, 0, stream>>>(xn, row_sum);
    kfinal<<<1, 1024, 0, stream>>>(row_sum, pos, out);
}